// Round 8
// baseline (399.830 us; speedup 1.0000x reference)
//
#include <hip/hip_runtime.h>
#include <cstdint>
#include <cstddef>

typedef __attribute__((ext_vector_type(8))) _Float16 f16x8;
typedef __attribute__((ext_vector_type(8))) short bf16x8;
typedef __attribute__((ext_vector_type(4))) float f32x4;
typedef __attribute__((ext_vector_type(8))) unsigned short ushort8;

#define FIX_CAP 65536
// fp16 2-term flag margin: >9-sigma on pairwise logit-error difference +
// key-truncation slack. Harness-verified in round 5 (passed).
#define MARGIN2F 4.5e-3f

__device__ __forceinline__ unsigned short f2bf(float f) {
  union { float f; unsigned int u; } x; x.f = f;
  unsigned int r = (x.u + 0x7fffu + ((x.u >> 16) & 1u)) >> 16;  // RNE
  return (unsigned short)r;
}
__device__ __forceinline__ unsigned short f2h(float f) {
  union { _Float16 h; unsigned short u; } c; c.h = (_Float16)f; return c.u;
}
__device__ __forceinline__ float h2f(unsigned short u) {
  union { unsigned short u; _Float16 h; } c; c.u = u; return (float)c.h;
}
// monotone float -> sortable u32 ordinal
__device__ __forceinline__ unsigned int f2ord(float v) {
  unsigned int s = __float_as_uint(v);
  return s ^ ((unsigned int)((int)s >> 31) | 0x80000000u);
}
__device__ __forceinline__ float ord2f(unsigned int o) {
  unsigned int s = (o & 0x80000000u) ? (o ^ 0x80000000u) : ~o;
  return __uint_as_float(s);
}

// lgkm-only barrier: drains LDS ops but leaves global loads in flight
__device__ __forceinline__ void barrier_lgkm() {
  asm volatile("s_waitcnt lgkmcnt(0)" ::: "memory");
  __builtin_amdgcn_s_barrier();
}

// ---------------------------------------------------------------------------
// kprep: fused {zero Mt + cnt, W3->bf16, W1->hi/lo fp16, const[k]=W3[k,:]·b2+b3[k]}
// ---------------------------------------------------------------------------
__global__ __launch_bounds__(256) void kprep(
    float* __restrict__ Mt, int* __restrict__ cnt,
    const float* __restrict__ W3, unsigned short* __restrict__ W3b,
    const float* __restrict__ W1, unsigned short* __restrict__ w1h,
    unsigned short* __restrict__ w1l,
    const float* __restrict__ b2, const float* __restrict__ b3,
    float* __restrict__ constv) {
  __shared__ float red[4];
  const int bid = blockIdx.x;
  const int t = threadIdx.x;
  if (bid < 512) {
    int e = bid * 256 + t;  // 2 MB of zeros
    ((float4*)Mt)[e] = (float4){0.f, 0.f, 0.f, 0.f};
    if (e == 0) cnt[0] = 0;
  } else if (bid < 768) {
    int e = ((bid - 512) * 256 + t) * 8;  // W3 -> bf16
    float4 f0 = *(const float4*)(W3 + e);
    float4 f1 = *(const float4*)(W3 + e + 4);
    ushort8 v;
    v[0] = f2bf(f0.x); v[1] = f2bf(f0.y); v[2] = f2bf(f0.z); v[3] = f2bf(f0.w);
    v[4] = f2bf(f1.x); v[5] = f2bf(f1.y); v[6] = f2bf(f1.z); v[7] = f2bf(f1.w);
    *(ushort8*)(W3b + e) = v;
  } else if (bid < 1024) {
    int e = ((bid - 768) * 256 + t) * 8;  // W1 -> hi/lo fp16
    float ff[8];
    *(float4*)&ff[0] = *(const float4*)(W1 + e);
    *(float4*)&ff[4] = *(const float4*)(W1 + e + 4);
    ushort8 h, l;
#pragma unroll
    for (int i = 0; i < 8; i++) {
      unsigned short hi = f2h(ff[i]);
      h[i] = hi;
      l[i] = f2h(ff[i] - h2f(hi));
    }
    *(ushort8*)(w1h + e) = h;
    *(ushort8*)(w1l + e) = l;
  } else {
    int k = bid - 1024;  // const[k]
    float s = 0.f;
    for (int j = t; j < 4096; j += 256) s += W3[k * 4096 + j] * b2[j];
#pragma unroll
    for (int mk = 1; mk < 64; mk <<= 1) s += __shfl_xor(s, mk, 64);
    if ((t & 63) == 0) red[t >> 6] = s;
    __syncthreads();
    if (t == 0) constv[k] = red[0] + red[1] + red[2] + red[3] + b3[k];
  }
}

// ---------------------------------------------------------------------------
// K1 v8 = r7 skeleton (512x512, swapped operands, 1 lgkm barrier/seg,
// distributed merge) with:
//   - fp16 2-term MFMA: mfma(wh,x)+mfma(wl,x), x fp16-staged once.
//     (accumulation order == round-5's harness-passed kernel -> identical
//     logits; flag margin 4.5e-3 proven there). MFMA/seg 96->64, x-LDS
//     reads halve.
//   - explicit cross-seg prefetch of next seg's ks=0 A-frags (the asm
//     barrier blocks compiler hoisting; must be in source). Cold-start L2
//     wait hides under epilogue+merge.
//   - bias loads hoisted above the MFMA loop (L2 latency hides under MFMA).
// ---------------------------------------------------------------------------
__global__ __launch_bounds__(512, 4) void k1_mfma(
    const float* __restrict__ x, const unsigned short* __restrict__ w1h,
    const unsigned short* __restrict__ w1l, const float* __restrict__ b1,
    int* __restrict__ idxbuf, int* __restrict__ cnt, int* __restrict__ list) {
  __shared__ unsigned short xsh[64 * 136];  // fp16 x tile, stride 136
  __shared__ uint2 wavebuf[2][8 * 64];      // double-buffered [wave][row] pairs

  const int t = threadIdx.x;
  const int r0 = blockIdx.x * 64;

  // ---- stage x rows 64x128 -> fp16 (once per block) ----
#pragma unroll
  for (int it = 0; it < 2; it++) {
    int ch = it * 512 + t;          // 1024 chunks of 8 elems
    int row = ch >> 4, k8 = ch & 15;
    float ff[8];
    *(float4*)&ff[0] = *(const float4*)(x + (r0 + row) * 128 + k8 * 8);
    *(float4*)&ff[4] = *(const float4*)(x + (r0 + row) * 128 + k8 * 8 + 4);
    ushort8 h;
#pragma unroll
    for (int i = 0; i < 8; i++) h[i] = f2h(ff[i]);
    *(ushort8*)&xsh[row * 136 + k8 * 8] = h;
  }
  __syncthreads();

  const int lane = t & 63, w = t >> 6;      // 8 waves
  const int m = lane & 15, q = lane >> 4;

  // A-frag byte offset helper: seg/a/ks -> element offset in w1h/w1l
  // row = seg*256 + w*32 + a*16 + m ; col = ks*32 + q*8
#define AOFF(seg_, a_, ks_) ((size_t)(((seg_) * 256 + w * 32 + (a_) * 16 + m)) * 128 + (ks_) * 32 + q * 8)

  // prefetch seg 0, ks 0
  f16x8 pah[2], pal[2];
#pragma unroll
  for (int a = 0; a < 2; a++) {
    pah[a] = *(const f16x8*)(w1h + AOFF(0, a, 0));
    pal[a] = *(const f16x8*)(w1l + AOFF(0, a, 0));
  }

  for (int seg = 0; seg < 16; ++seg) {
    const int cb = seg * 256 + w * 32;      // wave's first seg-col

    f32x4 acc[2][4];
#pragma unroll
    for (int a = 0; a < 2; a++)
#pragma unroll
      for (int b = 0; b < 4; b++) acc[a][b] = (f32x4){0.f, 0.f, 0.f, 0.f};

    // bias loads issued early: L2 latency hides under the MFMA loop
    float4 bias4[2];
#pragma unroll
    for (int a = 0; a < 2; a++)
      bias4[a] = *(const float4*)&b1[cb + a * 16 + q * 4];

#pragma unroll
    for (int ks = 0; ks < 4; ks++) {
      const int k0 = ks * 32;
      f16x8 ah[2], al[2];
      if (ks == 0) {
        ah[0] = pah[0]; ah[1] = pah[1];
        al[0] = pal[0]; al[1] = pal[1];
      } else {
#pragma unroll
        for (int a = 0; a < 2; a++) {
          ah[a] = *(const f16x8*)(w1h + AOFF(seg, a, ks));
          al[a] = *(const f16x8*)(w1l + AOFF(seg, a, ks));
        }
      }
#pragma unroll
      for (int b = 0; b < 4; b++) {
        f16x8 bx = *(const f16x8*)&xsh[(b * 16 + m) * 136 + k0 + q * 8];
#pragma unroll
        for (int a = 0; a < 2; a++) {
          acc[a][b] = __builtin_amdgcn_mfma_f32_16x16x32_f16(ah[a], bx, acc[a][b], 0, 0, 0);
          acc[a][b] = __builtin_amdgcn_mfma_f32_16x16x32_f16(al[a], bx, acc[a][b], 0, 0, 0);
        }
      }
    }

    // prefetch next seg's ks=0 A-frags: latency hides under epilogue+merge
    if (seg + 1 < 16) {
#pragma unroll
      for (int a = 0; a < 2; a++) {
        pah[a] = *(const f16x8*)(w1h + AOFF(seg + 1, a, 0));
        pal[a] = *(const f16x8*)(w1l + AOFF(seg + 1, a, 0));
      }
    }

    // ---- epilogue: per-row top-2 keys (r4/r7 proven math) ----
#pragma unroll
    for (int b = 0; b < 4; b++) {
      unsigned int K1 = 0u, K2 = 0u;
#pragma unroll
      for (int a = 0; a < 2; a++)
#pragma unroll
        for (int r = 0; r < 4; r++) {
          float v = acc[a][b][r] + bias4[a][r];
          unsigned int col = (unsigned)(w * 32 + a * 16 + q * 4 + r);
          unsigned int key = (f2ord(v) & 0xFFFFFF00u) | (255u - col);
          unsigned int mx = K1 > key ? K1 : key;
          unsigned int mn = K1 > key ? key : K1;
          K1 = mx; K2 = K2 > mn ? K2 : mn;
        }
#pragma unroll
      for (int msk = 16; msk <= 32; msk <<= 1) {
        unsigned int p1 = (unsigned int)__shfl_xor((int)K1, msk, 64);
        unsigned int p2 = (unsigned int)__shfl_xor((int)K2, msk, 64);
        unsigned int mx = K1 > p1 ? K1 : p1;
        unsigned int mn = K1 > p1 ? p1 : K1;
        unsigned int sel = K1 >= p1 ? K2 : p2;
        K1 = mx;
        K2 = sel > mn ? sel : mn;
      }
      if (lane < 16) {  // q == 0
        uint2 pr; pr.x = K1; pr.y = K2;
        wavebuf[seg & 1][w * 64 + b * 16 + m] = pr;
      }
    }

    barrier_lgkm();  // wavebuf[seg&1] visible; globals stay in flight

    // ---- distributed merge: lane<8 of wave w handles rows w*8..w*8+7 ----
    if (lane < 8) {
      const int row = w * 8 + lane;
      unsigned int K1 = 0u, K2 = 0u;
#pragma unroll
      for (int wp = 0; wp < 8; wp++) {
        uint2 pr = wavebuf[seg & 1][wp * 64 + row];
        unsigned int mx = K1 > pr.x ? K1 : pr.x;
        unsigned int mn = K1 > pr.x ? pr.x : K1;
        unsigned int sel = K1 >= pr.x ? K2 : pr.y;
        K1 = mx;
        K2 = sel > mn ? sel : mn;
      }
      int colw = 255 - (int)(K1 & 255u);
      int bgl = r0 + row;
      idxbuf[bgl * 16 + seg] = colw;
      float v1 = ord2f(K1 & 0xFFFFFF00u);
      float v2 = ord2f(K2 & 0xFFFFFF00u);
      if (v1 - v2 < MARGIN2F) {
        int p = atomicAdd(cnt, 1);
        if (p < FIX_CAP) list[p] = (bgl << 4) | seg;
      }
    }
    // next seg writes wavebuf[(seg+1)&1] -> no second barrier needed
  }
#undef AOFF
}

// ---------------------------------------------------------------------------
// K1fix: exact fp32 recompute for flagged (b,seg) — proven numerics
// (ascending-k fmaf from b1[c], lowest-index argmax tie-break).
// ---------------------------------------------------------------------------
__global__ __launch_bounds__(256) void k1_fix(
    const float* __restrict__ x, const float* __restrict__ W1,
    const float* __restrict__ b1, const int* __restrict__ cnt,
    const int* __restrict__ list, int* __restrict__ idxbuf) {
  __shared__ float redv[4];
  __shared__ int   redi[4];
  const int t = threadIdx.x;
  const int lane = t & 63, wv = t >> 6;
  int n = cnt[0]; if (n > FIX_CAP) n = FIX_CAP;
  for (int e = blockIdx.x; e < n; e += gridDim.x) {
    int pk = list[e];
    int b = pk >> 4, seg = pk & 15;
    int c = seg * 256 + t;
    float a = b1[c];
    const float4* xr = (const float4*)(x + (size_t)b * 128);
    const float4* wr = (const float4*)(W1 + (size_t)c * 128);
#pragma unroll 8
    for (int k4 = 0; k4 < 32; k4++) {
      float4 xv = xr[k4];
      float4 wv4 = wr[k4];
      a = fmaf(xv.x, wv4.x, a);
      a = fmaf(xv.y, wv4.y, a);
      a = fmaf(xv.z, wv4.z, a);
      a = fmaf(xv.w, wv4.w, a);
    }
    float v = a; int li = t;
#pragma unroll
    for (int msk = 1; msk < 64; msk <<= 1) {
      float u = __shfl_xor(v, msk, 64);
      int ju = __shfl_xor(li, msk, 64);
      if (u > v || (u == v && ju < li)) { v = u; li = ju; }
    }
    if (lane == 0) { redv[wv] = v; redi[wv] = li; }
    __syncthreads();
    if (t == 0) {
      float bv = redv[0]; int bi = redi[0];
#pragma unroll
      for (int w = 1; w < 4; w++) {
        if (redv[w] > bv || (redv[w] == bv && redi[w] < bi)) { bv = redv[w]; bi = redi[w]; }
      }
      idxbuf[b * 16 + seg] = bi;
    }
    __syncthreads();
  }
}

// ---------------------------------------------------------------------------
// K2 (r7 proven): Mt[c,k] += sum_j W2[j,c]*W3[k,j], splitK=8, LDS-transposed
// staging, register prefetch of next iter's W2, lgkm-only barriers.
// ---------------------------------------------------------------------------
__global__ __launch_bounds__(256) void k2_mfma(const float* __restrict__ W2,
                                               const unsigned short* __restrict__ W3b,
                                               float* __restrict__ Mt) {
  __shared__ unsigned short ldsT[64 * 40];
  const int t = threadIdx.x;
  const int lane = t & 63, wv = t >> 6;
  const int c0 = blockIdx.x * 64;
  const int jq = blockIdx.y;
  const int m = lane & 15, q = lane >> 4;
  const int jl0 = t >> 4, cq0 = t & 15;            // fid = t
  const int jl1 = (256 + t) >> 4, cq1 = t & 15;    // fid = 256 + t
  f32x4 acc[8];
#pragma unroll
  for (int nt = 0; nt < 8; nt++) acc[nt] = (f32x4){0.f, 0.f, 0.f, 0.f};

  // preload it=0
  float4 p0 = *(const float4*)&W2[(size_t)(jq * 512 + jl0) * 4096 + c0 + cq0 * 4];
  float4 p1 = *(const float4*)&W2[(size_t)(jq * 512 + jl1) * 4096 + c0 + cq1 * 4];

  for (int it = 0; it < 16; it++) {
    const int j0 = jq * 512 + it * 32;
    ldsT[(cq0 * 4 + 0) * 40 + jl0] = f2bf(p0.x);
    ldsT[(cq0 * 4 + 1) * 40 + jl0] = f2bf(p0.y);
    ldsT[(cq0 * 4 + 2) * 40 + jl0] = f2bf(p0.z);
    ldsT[(cq0 * 4 + 3) * 40 + jl0] = f2bf(p0.w);
    ldsT[(cq1 * 4 + 0) * 40 + jl1] = f2bf(p1.x);
    ldsT[(cq1 * 4 + 1) * 40 + jl1] = f2bf(p1.y);
    ldsT[(cq1 * 4 + 2) * 40 + jl1] = f2bf(p1.z);
    ldsT[(cq1 * 4 + 3) * 40 + jl1] = f2bf(p1.w);
    barrier_lgkm();
    bf16x8 av = *(const bf16x8*)&ldsT[(wv * 16 + m) * 40 + q * 8];
    if (it + 1 < 16) {
      const int jn = j0 + 32;
      p0 = *(const float4*)&W2[(size_t)(jn + jl0) * 4096 + c0 + cq0 * 4];
      p1 = *(const float4*)&W2[(size_t)(jn + jl1) * 4096 + c0 + cq1 * 4];
    }
#pragma unroll
    for (int nt = 0; nt < 8; nt++) {
      bf16x8 b = *(const bf16x8*)(W3b + (nt * 16 + m) * 4096 + j0 + q * 8);
      acc[nt] = __builtin_amdgcn_mfma_f32_16x16x32_bf16(av, b, acc[nt], 0, 0, 0);
    }
    barrier_lgkm();  // av reads drained; ldsT safe to overwrite next iter
  }
#pragma unroll
  for (int nt = 0; nt < 8; nt++)
#pragma unroll
    for (int r = 0; r < 4; r++)
      atomicAdd(&Mt[(size_t)(c0 + wv * 16 + q * 4 + r) * 128 + nt * 16 + m], acc[nt][r]);
}

// ---------------------------------------------------------------------------
// K3: out[b,k] = const[k] + sum_g Mt[g*256 + idx[b,g], k]  (unchanged)
// ---------------------------------------------------------------------------
__global__ __launch_bounds__(256) void k3_gather(const int* __restrict__ idxbuf,
                                                 const float* __restrict__ Mt,
                                                 const float* __restrict__ constv,
                                                 float* __restrict__ out) {
  const int t = threadIdx.x;
  const int w = t >> 6;
  const int lane = t & 63;
  const int b = blockIdx.x * 4 + w;
  float a0 = constv[lane];
  float a1 = constv[lane + 64];
  const int* ib = idxbuf + b * 16;
  int cg[16];
#pragma unroll
  for (int g = 0; g < 16; g++) cg[g] = g * 256 + ib[g];
#pragma unroll
  for (int g = 0; g < 16; g++) {
    const float* mrow = Mt + (size_t)cg[g] * 128;
    a0 += mrow[lane];
    a1 += mrow[lane + 64];
  }
  out[b * 128 + lane] = a0;
  out[b * 128 + lane + 64] = a1;
}

// ---------------------------------------------------------------------------
extern "C" void kernel_launch(void* const* d_in, const int* in_sizes, int n_in,
                              void* d_out, int out_size, void* d_ws, size_t ws_size,
                              hipStream_t stream) {
  const float* x  = (const float*)d_in[0];
  const float* W1 = (const float*)d_in[1];
  const float* b1 = (const float*)d_in[2];
  const float* W2 = (const float*)d_in[3];
  const float* b2 = (const float*)d_in[4];
  const float* W3 = (const float*)d_in[5];
  const float* b3 = (const float*)d_in[6];
  float* out = (float*)d_out;

  char* w = (char*)d_ws;
  int* idxbuf         = (int*)(w);                           // 2 MB
  unsigned short* W3b = (unsigned short*)(w + (2u << 20));   // 1 MB
  float* Mt           = (float*)(w + (3u << 20));            // 2 MB
  unsigned short* w1h = (unsigned short*)(w + (5u << 20));   // 1 MB (fp16 hi)
  unsigned short* w1l = (unsigned short*)(w + (6u << 20));   // 1 MB (fp16 lo)
  float* constv       = (float*)(w + (7u << 20));            // 512 B
  int* cnt            = (int*)(w + (7u << 20) + 1024);       // 4 B
  int* fixlist        = (int*)(w + (7u << 20) + 4096);       // 256 KB

  kprep<<<1152, 256, 0, stream>>>(Mt, cnt, W3, W3b, W1, w1h, w1l, b2, b3, constv);
  k1_mfma<<<512, 512, 0, stream>>>(x, w1h, w1l, b1, idxbuf, cnt, fixlist);
  k1_fix<<<1024, 256, 0, stream>>>(x, W1, b1, cnt, fixlist, idxbuf);
  k2_mfma<<<dim3(64, 8), 256, 0, stream>>>(W2, W3b, Mt);
  k3_gather<<<8192, 256, 0, stream>>>(idxbuf, Mt, constv, out);
}

// Round 9
// 332.152 us; speedup vs baseline: 1.2038x; 1.2038x over previous
//
#include <hip/hip_runtime.h>
#include <cstdint>
#include <cstddef>

typedef __attribute__((ext_vector_type(8))) _Float16 f16x8;
typedef __attribute__((ext_vector_type(8))) short bf16x8;
typedef __attribute__((ext_vector_type(4))) float f32x4;
typedef __attribute__((ext_vector_type(8))) unsigned short ushort8;

#define CAPF 32768
#define CAP2 32768
// fp16 2-term flag margin (harness-verified in rounds 5 and 8)
#define MARGIN2F 4.5e-3f

__device__ __forceinline__ unsigned short f2bf(float f) {
  union { float f; unsigned int u; } x; x.f = f;
  unsigned int r = (x.u + 0x7fffu + ((x.u >> 16) & 1u)) >> 16;  // RNE
  return (unsigned short)r;
}
__device__ __forceinline__ unsigned short f2h(float f) {
  union { _Float16 h; unsigned short u; } c; c.h = (_Float16)f; return c.u;
}
__device__ __forceinline__ float h2f(unsigned short u) {
  union { unsigned short u; _Float16 h; } c; c.u = u; return (float)c.h;
}
// monotone float -> sortable u32 ordinal
__device__ __forceinline__ unsigned int f2ord(float v) {
  unsigned int s = __float_as_uint(v);
  return s ^ ((unsigned int)((int)s >> 31) | 0x80000000u);
}
__device__ __forceinline__ float ord2f(unsigned int o) {
  unsigned int s = (o & 0x80000000u) ? (o ^ 0x80000000u) : ~o;
  return __uint_as_float(s);
}

// lgkm-only barrier: drains LDS ops but leaves global loads in flight
__device__ __forceinline__ void barrier_lgkm() {
  asm volatile("s_waitcnt lgkmcnt(0)" ::: "memory");
  __builtin_amdgcn_s_barrier();
}

// ---------------------------------------------------------------------------
// kprep: fused {zero Mt + counters, W3->bf16, W1->hi/lo fp16, const vector}
// ---------------------------------------------------------------------------
__global__ __launch_bounds__(256) void kprep(
    float* __restrict__ Mt, int* __restrict__ cntF, int* __restrict__ cnt2,
    const float* __restrict__ W3, unsigned short* __restrict__ W3b,
    const float* __restrict__ W1, unsigned short* __restrict__ w1h,
    unsigned short* __restrict__ w1l,
    const float* __restrict__ b2, const float* __restrict__ b3,
    float* __restrict__ constv) {
  __shared__ float red[4];
  const int bid = blockIdx.x;
  const int t = threadIdx.x;
  if (bid < 512) {
    int e = bid * 256 + t;  // 2 MB of zeros
    ((float4*)Mt)[e] = (float4){0.f, 0.f, 0.f, 0.f};
    if (e == 0) { cntF[0] = 0; cnt2[0] = 0; }
  } else if (bid < 768) {
    int e = ((bid - 512) * 256 + t) * 8;  // W3 -> bf16
    float4 f0 = *(const float4*)(W3 + e);
    float4 f1 = *(const float4*)(W3 + e + 4);
    ushort8 v;
    v[0] = f2bf(f0.x); v[1] = f2bf(f0.y); v[2] = f2bf(f0.z); v[3] = f2bf(f0.w);
    v[4] = f2bf(f1.x); v[5] = f2bf(f1.y); v[6] = f2bf(f1.z); v[7] = f2bf(f1.w);
    *(ushort8*)(W3b + e) = v;
  } else if (bid < 1024) {
    int e = ((bid - 768) * 256 + t) * 8;  // W1 -> hi/lo fp16
    float ff[8];
    *(float4*)&ff[0] = *(const float4*)(W1 + e);
    *(float4*)&ff[4] = *(const float4*)(W1 + e + 4);
    ushort8 h, l;
#pragma unroll
    for (int i = 0; i < 8; i++) {
      unsigned short hi = f2h(ff[i]);
      h[i] = hi;
      l[i] = f2h(ff[i] - h2f(hi));
    }
    *(ushort8*)(w1h + e) = h;
    *(ushort8*)(w1l + e) = l;
  } else {
    int k = bid - 1024;  // const[k]
    float s = 0.f;
    for (int j = t; j < 4096; j += 256) s += W3[k * 4096 + j] * b2[j];
#pragma unroll
    for (int mk = 1; mk < 64; mk <<= 1) s += __shfl_xor(s, mk, 64);
    if ((t & 63) == 0) red[t >> 6] = s;
    __syncthreads();
    if (t == 0) constv[k] = red[0] + red[1] + red[2] + red[3] + b3[k];
  }
}

// ---------------------------------------------------------------------------
// K1 v9 = r8 kernel (154 µs, passed) with a two-tier flag classifier in the
// merge: track K3 = 3rd max of the 16 per-wave pair values.
//   - If i1,i2 in DIFFERENT waves, M3 == true union 3rd max (x1=M1, x2=M2,
//     and x3 must be some wave's K1 or K2). Then v1-v3 >= margin guarantees
//     exact argmax is in {i1,i2} -> cheap 2-col exact fixup.
//   - Same-wave(i1,i2) or v1-v3 < margin -> full 256-col fixup (proven path).
// Expected: ~12k 2-col + ~1.6k full (was: 12k full at ~8.7 us each).
// ---------------------------------------------------------------------------
__global__ __launch_bounds__(512, 4) void k1_mfma(
    const float* __restrict__ x, const unsigned short* __restrict__ w1h,
    const unsigned short* __restrict__ w1l, const float* __restrict__ b1,
    int* __restrict__ idxbuf, int* __restrict__ cntF, int* __restrict__ listF,
    int* __restrict__ cnt2, int2* __restrict__ list2) {
  __shared__ unsigned short xsh[64 * 136];  // fp16 x tile, stride 136
  __shared__ uint2 wavebuf[2][8 * 64];      // double-buffered [wave][row] pairs

  const int t = threadIdx.x;
  const int r0 = blockIdx.x * 64;

  // ---- stage x rows 64x128 -> fp16 (once per block) ----
#pragma unroll
  for (int it = 0; it < 2; it++) {
    int ch = it * 512 + t;          // 1024 chunks of 8 elems
    int row = ch >> 4, k8 = ch & 15;
    float ff[8];
    *(float4*)&ff[0] = *(const float4*)(x + (r0 + row) * 128 + k8 * 8);
    *(float4*)&ff[4] = *(const float4*)(x + (r0 + row) * 128 + k8 * 8 + 4);
    ushort8 h;
#pragma unroll
    for (int i = 0; i < 8; i++) h[i] = f2h(ff[i]);
    *(ushort8*)&xsh[row * 136 + k8 * 8] = h;
  }
  __syncthreads();

  const int lane = t & 63, w = t >> 6;      // 8 waves
  const int m = lane & 15, q = lane >> 4;

#define AOFF(seg_, a_, ks_) ((size_t)(((seg_) * 256 + w * 32 + (a_) * 16 + m)) * 128 + (ks_) * 32 + q * 8)

  // prefetch seg 0, ks 0
  f16x8 pah[2], pal[2];
#pragma unroll
  for (int a = 0; a < 2; a++) {
    pah[a] = *(const f16x8*)(w1h + AOFF(0, a, 0));
    pal[a] = *(const f16x8*)(w1l + AOFF(0, a, 0));
  }

  for (int seg = 0; seg < 16; ++seg) {
    const int cb = seg * 256 + w * 32;      // wave's first seg-col

    f32x4 acc[2][4];
#pragma unroll
    for (int a = 0; a < 2; a++)
#pragma unroll
      for (int b = 0; b < 4; b++) acc[a][b] = (f32x4){0.f, 0.f, 0.f, 0.f};

    // bias loads issued early: L2 latency hides under the MFMA loop
    float4 bias4[2];
#pragma unroll
    for (int a = 0; a < 2; a++)
      bias4[a] = *(const float4*)&b1[cb + a * 16 + q * 4];

#pragma unroll
    for (int ks = 0; ks < 4; ks++) {
      const int k0 = ks * 32;
      f16x8 ah[2], al[2];
      if (ks == 0) {
        ah[0] = pah[0]; ah[1] = pah[1];
        al[0] = pal[0]; al[1] = pal[1];
      } else {
#pragma unroll
        for (int a = 0; a < 2; a++) {
          ah[a] = *(const f16x8*)(w1h + AOFF(seg, a, ks));
          al[a] = *(const f16x8*)(w1l + AOFF(seg, a, ks));
        }
      }
#pragma unroll
      for (int b = 0; b < 4; b++) {
        f16x8 bx = *(const f16x8*)&xsh[(b * 16 + m) * 136 + k0 + q * 8];
#pragma unroll
        for (int a = 0; a < 2; a++) {
          acc[a][b] = __builtin_amdgcn_mfma_f32_16x16x32_f16(ah[a], bx, acc[a][b], 0, 0, 0);
          acc[a][b] = __builtin_amdgcn_mfma_f32_16x16x32_f16(al[a], bx, acc[a][b], 0, 0, 0);
        }
      }
    }

    // prefetch next seg's ks=0 A-frags: latency hides under epilogue+merge
    if (seg + 1 < 16) {
#pragma unroll
      for (int a = 0; a < 2; a++) {
        pah[a] = *(const f16x8*)(w1h + AOFF(seg + 1, a, 0));
        pal[a] = *(const f16x8*)(w1l + AOFF(seg + 1, a, 0));
      }
    }

    // ---- epilogue: per-row top-2 keys (proven math) ----
#pragma unroll
    for (int b = 0; b < 4; b++) {
      unsigned int K1 = 0u, K2 = 0u;
#pragma unroll
      for (int a = 0; a < 2; a++)
#pragma unroll
        for (int r = 0; r < 4; r++) {
          float v = acc[a][b][r] + bias4[a][r];
          unsigned int col = (unsigned)(w * 32 + a * 16 + q * 4 + r);
          unsigned int key = (f2ord(v) & 0xFFFFFF00u) | (255u - col);
          unsigned int mx = K1 > key ? K1 : key;
          unsigned int mn = K1 > key ? key : K1;
          K1 = mx; K2 = K2 > mn ? K2 : mn;
        }
#pragma unroll
      for (int msk = 16; msk <= 32; msk <<= 1) {
        unsigned int p1 = (unsigned int)__shfl_xor((int)K1, msk, 64);
        unsigned int p2 = (unsigned int)__shfl_xor((int)K2, msk, 64);
        unsigned int mx = K1 > p1 ? K1 : p1;
        unsigned int mn = K1 > p1 ? p1 : K1;
        unsigned int sel = K1 >= p1 ? K2 : p2;
        K1 = mx;
        K2 = sel > mn ? sel : mn;
      }
      if (lane < 16) {  // q == 0
        uint2 pr; pr.x = K1; pr.y = K2;
        wavebuf[seg & 1][w * 64 + b * 16 + m] = pr;
      }
    }

    barrier_lgkm();  // wavebuf[seg&1] visible; globals stay in flight

    // ---- distributed merge + two-tier classification (lane<8 per wave) ----
    if (lane < 8) {
      const int row = w * 8 + lane;
      unsigned int K1 = 0u, K2 = 0u, K3 = 0u;
#pragma unroll
      for (int wp = 0; wp < 8; wp++) {
        uint2 pr = wavebuf[seg & 1][wp * 64 + row];
        // bubble-insert pr.x then pr.y into sorted (K1,K2,K3)
        unsigned int v0 = pr.x;
        unsigned int t1 = K1 > v0 ? K1 : v0, b1_ = K1 > v0 ? v0 : K1;
        unsigned int t2 = K2 > b1_ ? K2 : b1_, b2_ = K2 > b1_ ? b1_ : K2;
        K1 = t1; K2 = t2; K3 = K3 > b2_ ? K3 : b2_;
        v0 = pr.y;
        t1 = K1 > v0 ? K1 : v0; b1_ = K1 > v0 ? v0 : K1;
        t2 = K2 > b1_ ? K2 : b1_; b2_ = K2 > b1_ ? b1_ : K2;
        K1 = t1; K2 = t2; K3 = K3 > b2_ ? K3 : b2_;
      }
      int colw = 255 - (int)(K1 & 255u);
      int col2 = 255 - (int)(K2 & 255u);
      int bgl = r0 + row;
      idxbuf[bgl * 16 + seg] = colw;
      float v1 = ord2f(K1 & 0xFFFFFF00u);
      float v2 = ord2f(K2 & 0xFFFFFF00u);
      float v3 = ord2f(K3 & 0xFFFFFF00u);
      if (v1 - v2 < MARGIN2F) {
        int pk = (bgl << 4) | seg;
        // full if top-2 share a wave (M3 may under-estimate true 3rd) or
        // 3rd max is also within the margin of v1
        bool full = ((colw >> 5) == (col2 >> 5)) || (v1 - v3 < MARGIN2F);
        if (full) {
          int p = atomicAdd(cntF, 1);
          if (p < CAPF) listF[p] = pk;
        } else {
          int p = atomicAdd(cnt2, 1);
          if (p < CAP2) {
            list2[p] = (int2){pk, (colw << 8) | col2};
          } else {  // overflow: full fix is a correct superset handler
            int pf = atomicAdd(cntF, 1);
            if (pf < CAPF) listF[pf] = pk;
          }
        }
      }
    }
    // next seg writes wavebuf[(seg+1)&1] -> no second barrier needed
  }
#undef AOFF
}

// ---------------------------------------------------------------------------
// K1fix: phase 1 = full 256-col exact recompute (proven r1 numerics) for
// entries in listF; phase 2 = 2-col exact compare for entries in list2
// (one entry per thread; per-column fmaf order identical to phase 1).
// ---------------------------------------------------------------------------
__global__ __launch_bounds__(256) void k1_fix(
    const float* __restrict__ x, const float* __restrict__ W1,
    const float* __restrict__ b1,
    const int* __restrict__ cntF, const int* __restrict__ listF,
    const int* __restrict__ cnt2, const int2* __restrict__ list2,
    int* __restrict__ idxbuf) {
  __shared__ float redv[4];
  __shared__ int   redi[4];
  const int t = threadIdx.x;
  const int lane = t & 63, wv = t >> 6;

  // ---- phase 1: full fixups ----
  int nf = cntF[0]; if (nf > CAPF) nf = CAPF;
  for (int e = blockIdx.x; e < nf; e += gridDim.x) {
    int pk = listF[e];
    int b = pk >> 4, seg = pk & 15;
    int c = seg * 256 + t;
    float a = b1[c];
    const float4* xr = (const float4*)(x + (size_t)b * 128);
    const float4* wr = (const float4*)(W1 + (size_t)c * 128);
#pragma unroll 8
    for (int k4 = 0; k4 < 32; k4++) {
      float4 xv = xr[k4];
      float4 wv4 = wr[k4];
      a = fmaf(xv.x, wv4.x, a);
      a = fmaf(xv.y, wv4.y, a);
      a = fmaf(xv.z, wv4.z, a);
      a = fmaf(xv.w, wv4.w, a);
    }
    float v = a; int li = t;
#pragma unroll
    for (int msk = 1; msk < 64; msk <<= 1) {
      float u = __shfl_xor(v, msk, 64);
      int ju = __shfl_xor(li, msk, 64);
      if (u > v || (u == v && ju < li)) { v = u; li = ju; }
    }
    if (lane == 0) { redv[wv] = v; redi[wv] = li; }
    __syncthreads();
    if (t == 0) {
      float bv = redv[0]; int bi = redi[0];
#pragma unroll
      for (int w = 1; w < 4; w++) {
        if (redv[w] > bv || (redv[w] == bv && redi[w] < bi)) { bv = redv[w]; bi = redi[w]; }
      }
      idxbuf[b * 16 + seg] = bi;
    }
    __syncthreads();
  }

  // ---- phase 2: 2-col fixups (one per thread) ----
  int n2 = cnt2[0]; if (n2 > CAP2) n2 = CAP2;
  for (int e = blockIdx.x * 256 + t; e < n2; e += gridDim.x * 256) {
    int2 en = list2[e];
    int pk = en.x;
    int b = pk >> 4, seg = pk & 15;
    int i1 = (en.y >> 8) & 255, i2 = en.y & 255;
    int c1 = seg * 256 + i1, c2 = seg * 256 + i2;
    const float* xr = x + (size_t)b * 128;
    const float* w1r = W1 + (size_t)c1 * 128;
    const float* w2r = W1 + (size_t)c2 * 128;
    float a1 = b1[c1], a2 = b1[c2];
#pragma unroll 16
    for (int k = 0; k < 128; k++) {
      float xv = xr[k];
      a1 = fmaf(xv, w1r[k], a1);
      a2 = fmaf(xv, w2r[k], a2);
    }
    int win = (a1 > a2) ? i1 : (a2 > a1) ? i2 : (i1 < i2 ? i1 : i2);
    idxbuf[b * 16 + seg] = win;
  }
}

// ---------------------------------------------------------------------------
// K2 (r7/r8 proven): Mt[c,k] += sum_j W2[j,c]*W3[k,j], splitK=8,
// LDS-transposed staging, register prefetch, lgkm-only barriers.
// ---------------------------------------------------------------------------
__global__ __launch_bounds__(256) void k2_mfma(const float* __restrict__ W2,
                                               const unsigned short* __restrict__ W3b,
                                               float* __restrict__ Mt) {
  __shared__ unsigned short ldsT[64 * 40];
  const int t = threadIdx.x;
  const int lane = t & 63, wv = t >> 6;
  const int c0 = blockIdx.x * 64;
  const int jq = blockIdx.y;
  const int m = lane & 15, q = lane >> 4;
  const int jl0 = t >> 4, cq0 = t & 15;            // fid = t
  const int jl1 = (256 + t) >> 4, cq1 = t & 15;    // fid = 256 + t
  f32x4 acc[8];
#pragma unroll
  for (int nt = 0; nt < 8; nt++) acc[nt] = (f32x4){0.f, 0.f, 0.f, 0.f};

  // preload it=0
  float4 p0 = *(const float4*)&W2[(size_t)(jq * 512 + jl0) * 4096 + c0 + cq0 * 4];
  float4 p1 = *(const float4*)&W2[(size_t)(jq * 512 + jl1) * 4096 + c0 + cq1 * 4];

  for (int it = 0; it < 16; it++) {
    const int j0 = jq * 512 + it * 32;
    ldsT[(cq0 * 4 + 0) * 40 + jl0] = f2bf(p0.x);
    ldsT[(cq0 * 4 + 1) * 40 + jl0] = f2bf(p0.y);
    ldsT[(cq0 * 4 + 2) * 40 + jl0] = f2bf(p0.z);
    ldsT[(cq0 * 4 + 3) * 40 + jl0] = f2bf(p0.w);
    ldsT[(cq1 * 4 + 0) * 40 + jl1] = f2bf(p1.x);
    ldsT[(cq1 * 4 + 1) * 40 + jl1] = f2bf(p1.y);
    ldsT[(cq1 * 4 + 2) * 40 + jl1] = f2bf(p1.z);
    ldsT[(cq1 * 4 + 3) * 40 + jl1] = f2bf(p1.w);
    barrier_lgkm();
    bf16x8 av = *(const bf16x8*)&ldsT[(wv * 16 + m) * 40 + q * 8];
    if (it + 1 < 16) {
      const int jn = j0 + 32;
      p0 = *(const float4*)&W2[(size_t)(jn + jl0) * 4096 + c0 + cq0 * 4];
      p1 = *(const float4*)&W2[(size_t)(jn + jl1) * 4096 + c0 + cq1 * 4];
    }
#pragma unroll
    for (int nt = 0; nt < 8; nt++) {
      bf16x8 b = *(const bf16x8*)(W3b + (nt * 16 + m) * 4096 + j0 + q * 8);
      acc[nt] = __builtin_amdgcn_mfma_f32_16x16x32_bf16(av, b, acc[nt], 0, 0, 0);
    }
    barrier_lgkm();  // av reads drained; ldsT safe to overwrite next iter
  }
#pragma unroll
  for (int nt = 0; nt < 8; nt++)
#pragma unroll
    for (int r = 0; r < 4; r++)
      atomicAdd(&Mt[(size_t)(c0 + wv * 16 + q * 4 + r) * 128 + nt * 16 + m], acc[nt][r]);
}

// ---------------------------------------------------------------------------
// K3: out[b,k] = const[k] + sum_g Mt[g*256 + idx[b,g], k]  (unchanged)
// ---------------------------------------------------------------------------
__global__ __launch_bounds__(256) void k3_gather(const int* __restrict__ idxbuf,
                                                 const float* __restrict__ Mt,
                                                 const float* __restrict__ constv,
                                                 float* __restrict__ out) {
  const int t = threadIdx.x;
  const int w = t >> 6;
  const int lane = t & 63;
  const int b = blockIdx.x * 4 + w;
  float a0 = constv[lane];
  float a1 = constv[lane + 64];
  const int* ib = idxbuf + b * 16;
  int cg[16];
#pragma unroll
  for (int g = 0; g < 16; g++) cg[g] = g * 256 + ib[g];
#pragma unroll
  for (int g = 0; g < 16; g++) {
    const float* mrow = Mt + (size_t)cg[g] * 128;
    a0 += mrow[lane];
    a1 += mrow[lane + 64];
  }
  out[b * 128 + lane] = a0;
  out[b * 128 + lane + 64] = a1;
}

// ---------------------------------------------------------------------------
extern "C" void kernel_launch(void* const* d_in, const int* in_sizes, int n_in,
                              void* d_out, int out_size, void* d_ws, size_t ws_size,
                              hipStream_t stream) {
  const float* x  = (const float*)d_in[0];
  const float* W1 = (const float*)d_in[1];
  const float* b1 = (const float*)d_in[2];
  const float* W2 = (const float*)d_in[3];
  const float* b2 = (const float*)d_in[4];
  const float* W3 = (const float*)d_in[5];
  const float* b3 = (const float*)d_in[6];
  float* out = (float*)d_out;

  char* w = (char*)d_ws;
  int* idxbuf         = (int*)(w);                              // 2 MB
  unsigned short* W3b = (unsigned short*)(w + (2u << 20));      // 1 MB
  float* Mt           = (float*)(w + (3u << 20));               // 2 MB
  unsigned short* w1h = (unsigned short*)(w + (5u << 20));      // 1 MB (fp16 hi)
  unsigned short* w1l = (unsigned short*)(w + (6u << 20));      // 1 MB (fp16 lo)
  float* constv       = (float*)(w + (7u << 20));               // 512 B
  int* cntF           = (int*)(w + (7u << 20) + 1024);          // 4 B
  int* cnt2           = (int*)(w + (7u << 20) + 1280);          // 4 B (own line)
  int* listF          = (int*)(w + (7u << 20) + 4096);          // 128 KB
  int2* list2         = (int2*)(w + (7u << 20) + 139264);       // 256 KB

  kprep<<<1152, 256, 0, stream>>>(Mt, cntF, cnt2, W3, W3b, W1, w1h, w1l, b2, b3, constv);
  k1_mfma<<<512, 512, 0, stream>>>(x, w1h, w1l, b1, idxbuf, cntF, listF, cnt2, list2);
  k1_fix<<<2048, 256, 0, stream>>>(x, W1, b1, cntF, listF, cnt2, list2, idxbuf);
  k2_mfma<<<dim3(64, 8), 256, 0, stream>>>(W2, W3b, Mt);
  k3_gather<<<8192, 256, 0, stream>>>(idxbuf, Mt, constv, out);
}

// Round 10
// 331.290 us; speedup vs baseline: 1.2069x; 1.0026x over previous
//
#include <hip/hip_runtime.h>
#include <cstdint>
#include <cstddef>

typedef __attribute__((ext_vector_type(8))) _Float16 f16x8;
typedef __attribute__((ext_vector_type(8))) short bf16x8;
typedef __attribute__((ext_vector_type(4))) float f32x4;
typedef __attribute__((ext_vector_type(8))) unsigned short ushort8;

#define CAPF 32768
#define CAP2 32768
// fp16 2-term flag margin (harness-verified in rounds 5, 8, 9)
#define MARGIN2F 4.5e-3f

__device__ __forceinline__ unsigned short f2bf(float f) {
  union { float f; unsigned int u; } x; x.f = f;
  unsigned int r = (x.u + 0x7fffu + ((x.u >> 16) & 1u)) >> 16;  // RNE
  return (unsigned short)r;
}
// packed f32x2 -> bf16x2 (RNE, bit-identical to f2bf for normal values):
// dst.lo16 = bf16(a), dst.hi16 = bf16(b)
__device__ __forceinline__ unsigned int cvtpk_bf16(float a, float b) {
  unsigned int d;
  asm("v_cvt_pk_bf16_f32 %0, %1, %2" : "=v"(d) : "v"(a), "v"(b));
  return d;
}
__device__ __forceinline__ unsigned short f2h(float f) {
  union { _Float16 h; unsigned short u; } c; c.h = (_Float16)f; return c.u;
}
__device__ __forceinline__ float h2f(unsigned short u) {
  union { unsigned short u; _Float16 h; } c; c.u = u; return (float)c.h;
}
// monotone float -> sortable u32 ordinal
__device__ __forceinline__ unsigned int f2ord(float v) {
  unsigned int s = __float_as_uint(v);
  return s ^ ((unsigned int)((int)s >> 31) | 0x80000000u);
}
__device__ __forceinline__ float ord2f(unsigned int o) {
  unsigned int s = (o & 0x80000000u) ? (o ^ 0x80000000u) : ~o;
  return __uint_as_float(s);
}

// lgkm-only barrier: drains LDS ops but leaves global loads in flight
__device__ __forceinline__ void barrier_lgkm() {
  asm volatile("s_waitcnt lgkmcnt(0)" ::: "memory");
  __builtin_amdgcn_s_barrier();
}

// ---------------------------------------------------------------------------
// kprep: fused {zero Mt + counters, W3->bf16 (cvt_pk), W1->hi/lo fp16, const}
// ---------------------------------------------------------------------------
__global__ __launch_bounds__(256) void kprep(
    float* __restrict__ Mt, int* __restrict__ cntF, int* __restrict__ cnt2,
    const float* __restrict__ W3, unsigned short* __restrict__ W3b,
    const float* __restrict__ W1, unsigned short* __restrict__ w1h,
    unsigned short* __restrict__ w1l,
    const float* __restrict__ b2, const float* __restrict__ b3,
    float* __restrict__ constv) {
  __shared__ float red[4];
  const int bid = blockIdx.x;
  const int t = threadIdx.x;
  if (bid < 512) {
    int e = bid * 256 + t;  // 2 MB of zeros
    ((float4*)Mt)[e] = (float4){0.f, 0.f, 0.f, 0.f};
    if (e == 0) { cntF[0] = 0; cnt2[0] = 0; }
  } else if (bid < 768) {
    int e = ((bid - 512) * 256 + t) * 8;  // W3 -> bf16 via cvt_pk
    float4 f0 = *(const float4*)(W3 + e);
    float4 f1 = *(const float4*)(W3 + e + 4);
    uint4 v;
    v.x = cvtpk_bf16(f0.x, f0.y);
    v.y = cvtpk_bf16(f0.z, f0.w);
    v.z = cvtpk_bf16(f1.x, f1.y);
    v.w = cvtpk_bf16(f1.z, f1.w);
    *(uint4*)(W3b + e) = v;
  } else if (bid < 1024) {
    int e = ((bid - 768) * 256 + t) * 8;  // W1 -> hi/lo fp16
    float ff[8];
    *(float4*)&ff[0] = *(const float4*)(W1 + e);
    *(float4*)&ff[4] = *(const float4*)(W1 + e + 4);
    ushort8 h, l;
#pragma unroll
    for (int i = 0; i < 8; i++) {
      unsigned short hi = f2h(ff[i]);
      h[i] = hi;
      l[i] = f2h(ff[i] - h2f(hi));
    }
    *(ushort8*)(w1h + e) = h;
    *(ushort8*)(w1l + e) = l;
  } else {
    int k = bid - 1024;  // const[k]
    float s = 0.f;
    for (int j = t; j < 4096; j += 256) s += W3[k * 4096 + j] * b2[j];
#pragma unroll
    for (int mk = 1; mk < 64; mk <<= 1) s += __shfl_xor(s, mk, 64);
    if ((t & 63) == 0) red[t >> 6] = s;
    __syncthreads();
    if (t == 0) constv[k] = red[0] + red[1] + red[2] + red[3] + b3[k];
  }
}

// ---------------------------------------------------------------------------
// K1 (r9, harness-passed, 155 µs): fp16 2-term, swapped operands, 1 lgkm
// barrier/seg, distributed merge + two-tier flag classifier. UNCHANGED.
// ---------------------------------------------------------------------------
__global__ __launch_bounds__(512, 4) void k1_mfma(
    const float* __restrict__ x, const unsigned short* __restrict__ w1h,
    const unsigned short* __restrict__ w1l, const float* __restrict__ b1,
    int* __restrict__ idxbuf, int* __restrict__ cntF, int* __restrict__ listF,
    int* __restrict__ cnt2, int2* __restrict__ list2) {
  __shared__ unsigned short xsh[64 * 136];  // fp16 x tile, stride 136
  __shared__ uint2 wavebuf[2][8 * 64];      // double-buffered [wave][row] pairs

  const int t = threadIdx.x;
  const int r0 = blockIdx.x * 64;

  // ---- stage x rows 64x128 -> fp16 (once per block) ----
#pragma unroll
  for (int it = 0; it < 2; it++) {
    int ch = it * 512 + t;          // 1024 chunks of 8 elems
    int row = ch >> 4, k8 = ch & 15;
    float ff[8];
    *(float4*)&ff[0] = *(const float4*)(x + (r0 + row) * 128 + k8 * 8);
    *(float4*)&ff[4] = *(const float4*)(x + (r0 + row) * 128 + k8 * 8 + 4);
    ushort8 h;
#pragma unroll
    for (int i = 0; i < 8; i++) h[i] = f2h(ff[i]);
    *(ushort8*)&xsh[row * 136 + k8 * 8] = h;
  }
  __syncthreads();

  const int lane = t & 63, w = t >> 6;      // 8 waves
  const int m = lane & 15, q = lane >> 4;

#define AOFF(seg_, a_, ks_) ((size_t)(((seg_) * 256 + w * 32 + (a_) * 16 + m)) * 128 + (ks_) * 32 + q * 8)

  // prefetch seg 0, ks 0
  f16x8 pah[2], pal[2];
#pragma unroll
  for (int a = 0; a < 2; a++) {
    pah[a] = *(const f16x8*)(w1h + AOFF(0, a, 0));
    pal[a] = *(const f16x8*)(w1l + AOFF(0, a, 0));
  }

  for (int seg = 0; seg < 16; ++seg) {
    const int cb = seg * 256 + w * 32;      // wave's first seg-col

    f32x4 acc[2][4];
#pragma unroll
    for (int a = 0; a < 2; a++)
#pragma unroll
      for (int b = 0; b < 4; b++) acc[a][b] = (f32x4){0.f, 0.f, 0.f, 0.f};

    // bias loads issued early: L2 latency hides under the MFMA loop
    float4 bias4[2];
#pragma unroll
    for (int a = 0; a < 2; a++)
      bias4[a] = *(const float4*)&b1[cb + a * 16 + q * 4];

#pragma unroll
    for (int ks = 0; ks < 4; ks++) {
      const int k0 = ks * 32;
      f16x8 ah[2], al[2];
      if (ks == 0) {
        ah[0] = pah[0]; ah[1] = pah[1];
        al[0] = pal[0]; al[1] = pal[1];
      } else {
#pragma unroll
        for (int a = 0; a < 2; a++) {
          ah[a] = *(const f16x8*)(w1h + AOFF(seg, a, ks));
          al[a] = *(const f16x8*)(w1l + AOFF(seg, a, ks));
        }
      }
#pragma unroll
      for (int b = 0; b < 4; b++) {
        f16x8 bx = *(const f16x8*)&xsh[(b * 16 + m) * 136 + k0 + q * 8];
#pragma unroll
        for (int a = 0; a < 2; a++) {
          acc[a][b] = __builtin_amdgcn_mfma_f32_16x16x32_f16(ah[a], bx, acc[a][b], 0, 0, 0);
          acc[a][b] = __builtin_amdgcn_mfma_f32_16x16x32_f16(al[a], bx, acc[a][b], 0, 0, 0);
        }
      }
    }

    // prefetch next seg's ks=0 A-frags: latency hides under epilogue+merge
    if (seg + 1 < 16) {
#pragma unroll
      for (int a = 0; a < 2; a++) {
        pah[a] = *(const f16x8*)(w1h + AOFF(seg + 1, a, 0));
        pal[a] = *(const f16x8*)(w1l + AOFF(seg + 1, a, 0));
      }
    }

    // ---- epilogue: per-row top-2 keys (proven math) ----
#pragma unroll
    for (int b = 0; b < 4; b++) {
      unsigned int K1 = 0u, K2 = 0u;
#pragma unroll
      for (int a = 0; a < 2; a++)
#pragma unroll
        for (int r = 0; r < 4; r++) {
          float v = acc[a][b][r] + bias4[a][r];
          unsigned int col = (unsigned)(w * 32 + a * 16 + q * 4 + r);
          unsigned int key = (f2ord(v) & 0xFFFFFF00u) | (255u - col);
          unsigned int mx = K1 > key ? K1 : key;
          unsigned int mn = K1 > key ? key : K1;
          K1 = mx; K2 = K2 > mn ? K2 : mn;
        }
#pragma unroll
      for (int msk = 16; msk <= 32; msk <<= 1) {
        unsigned int p1 = (unsigned int)__shfl_xor((int)K1, msk, 64);
        unsigned int p2 = (unsigned int)__shfl_xor((int)K2, msk, 64);
        unsigned int mx = K1 > p1 ? K1 : p1;
        unsigned int mn = K1 > p1 ? p1 : K1;
        unsigned int sel = K1 >= p1 ? K2 : p2;
        K1 = mx;
        K2 = sel > mn ? sel : mn;
      }
      if (lane < 16) {  // q == 0
        uint2 pr; pr.x = K1; pr.y = K2;
        wavebuf[seg & 1][w * 64 + b * 16 + m] = pr;
      }
    }

    barrier_lgkm();  // wavebuf[seg&1] visible; globals stay in flight

    // ---- distributed merge + two-tier classification (lane<8 per wave) ----
    if (lane < 8) {
      const int row = w * 8 + lane;
      unsigned int K1 = 0u, K2 = 0u, K3 = 0u;
#pragma unroll
      for (int wp = 0; wp < 8; wp++) {
        uint2 pr = wavebuf[seg & 1][wp * 64 + row];
        unsigned int v0 = pr.x;
        unsigned int t1 = K1 > v0 ? K1 : v0, b1_ = K1 > v0 ? v0 : K1;
        unsigned int t2 = K2 > b1_ ? K2 : b1_, b2_ = K2 > b1_ ? b1_ : K2;
        K1 = t1; K2 = t2; K3 = K3 > b2_ ? K3 : b2_;
        v0 = pr.y;
        t1 = K1 > v0 ? K1 : v0; b1_ = K1 > v0 ? v0 : K1;
        t2 = K2 > b1_ ? K2 : b1_; b2_ = K2 > b1_ ? b1_ : K2;
        K1 = t1; K2 = t2; K3 = K3 > b2_ ? K3 : b2_;
      }
      int colw = 255 - (int)(K1 & 255u);
      int col2 = 255 - (int)(K2 & 255u);
      int bgl = r0 + row;
      idxbuf[bgl * 16 + seg] = colw;
      float v1 = ord2f(K1 & 0xFFFFFF00u);
      float v2 = ord2f(K2 & 0xFFFFFF00u);
      float v3 = ord2f(K3 & 0xFFFFFF00u);
      if (v1 - v2 < MARGIN2F) {
        int pk = (bgl << 4) | seg;
        bool full = ((colw >> 5) == (col2 >> 5)) || (v1 - v3 < MARGIN2F);
        if (full) {
          int p = atomicAdd(cntF, 1);
          if (p < CAPF) listF[p] = pk;
        } else {
          int p = atomicAdd(cnt2, 1);
          if (p < CAP2) {
            list2[p] = (int2){pk, (colw << 8) | col2};
          } else {  // overflow: full fix is a correct superset handler
            int pf = atomicAdd(cntF, 1);
            if (pf < CAPF) listF[pf] = pk;
          }
        }
      }
    }
    // next seg writes wavebuf[(seg+1)&1] -> no second barrier needed
  }
#undef AOFF
}

// ---------------------------------------------------------------------------
// K1fix (r9, harness-passed): full 256-col exact recompute + 2-col exact
// compare. UNCHANGED.
// ---------------------------------------------------------------------------
__global__ __launch_bounds__(256) void k1_fix(
    const float* __restrict__ x, const float* __restrict__ W1,
    const float* __restrict__ b1,
    const int* __restrict__ cntF, const int* __restrict__ listF,
    const int* __restrict__ cnt2, const int2* __restrict__ list2,
    int* __restrict__ idxbuf) {
  __shared__ float redv[4];
  __shared__ int   redi[4];
  const int t = threadIdx.x;
  const int lane = t & 63, wv = t >> 6;

  // ---- phase 1: full fixups ----
  int nf = cntF[0]; if (nf > CAPF) nf = CAPF;
  for (int e = blockIdx.x; e < nf; e += gridDim.x) {
    int pk = listF[e];
    int b = pk >> 4, seg = pk & 15;
    int c = seg * 256 + t;
    float a = b1[c];
    const float4* xr = (const float4*)(x + (size_t)b * 128);
    const float4* wr = (const float4*)(W1 + (size_t)c * 128);
#pragma unroll 8
    for (int k4 = 0; k4 < 32; k4++) {
      float4 xv = xr[k4];
      float4 wv4 = wr[k4];
      a = fmaf(xv.x, wv4.x, a);
      a = fmaf(xv.y, wv4.y, a);
      a = fmaf(xv.z, wv4.z, a);
      a = fmaf(xv.w, wv4.w, a);
    }
    float v = a; int li = t;
#pragma unroll
    for (int msk = 1; msk < 64; msk <<= 1) {
      float u = __shfl_xor(v, msk, 64);
      int ju = __shfl_xor(li, msk, 64);
      if (u > v || (u == v && ju < li)) { v = u; li = ju; }
    }
    if (lane == 0) { redv[wv] = v; redi[wv] = li; }
    __syncthreads();
    if (t == 0) {
      float bv = redv[0]; int bi = redi[0];
#pragma unroll
      for (int w = 1; w < 4; w++) {
        if (redv[w] > bv || (redv[w] == bv && redi[w] < bi)) { bv = redv[w]; bi = redi[w]; }
      }
      idxbuf[b * 16 + seg] = bi;
    }
    __syncthreads();
  }

  // ---- phase 2: 2-col fixups (one per thread) ----
  int n2 = cnt2[0]; if (n2 > CAP2) n2 = CAP2;
  for (int e = blockIdx.x * 256 + t; e < n2; e += gridDim.x * 256) {
    int2 en = list2[e];
    int pk = en.x;
    int b = pk >> 4, seg = pk & 15;
    int i1 = (en.y >> 8) & 255, i2 = en.y & 255;
    int c1 = seg * 256 + i1, c2 = seg * 256 + i2;
    const float* xr = x + (size_t)b * 128;
    const float* w1r = W1 + (size_t)c1 * 128;
    const float* w2r = W1 + (size_t)c2 * 128;
    float a1 = b1[c1], a2 = b1[c2];
#pragma unroll 16
    for (int k = 0; k < 128; k++) {
      float xv = xr[k];
      a1 = fmaf(xv, w1r[k], a1);
      a2 = fmaf(xv, w2r[k], a2);
    }
    int win = (a1 > a2) ? i1 : (a2 > a1) ? i2 : (i1 < i2 ? i1 : i2);
    idxbuf[b * 16 + seg] = win;
  }
}

// ---------------------------------------------------------------------------
// K2 v10: conversion rewritten around v_cvt_pk_bf16_f32.
// Staging mapping: thread (jp = t>>4, cq = t&15) loads the same c-quad from
// two ADJACENT j-rows (2 coalesced float4s), then packs j-adjacent pairs:
// dword = cvt_pk(W2[2jp][c], W2[2jp+1][c]) -> ds_write_b32 at row c, dword jp.
// LDS [c][j] short layout identical to r9 (stride 40 shorts, j-order low-
// short-first) -> MFMA reads & inputs bit-identical. Per 8 values: 4 cvt_pk
// + 4 b32 writes (was ~32 VALU + 8 b16 writes) -> conversion VALU /8.
// SplitK=8, register prefetch, lgkm barriers: unchanged from r7/r9.
// ---------------------------------------------------------------------------
__global__ __launch_bounds__(256) void k2_mfma(const float* __restrict__ W2,
                                               const unsigned short* __restrict__ W3b,
                                               float* __restrict__ Mt) {
  __shared__ unsigned short ldsT[64 * 40];
  const int t = threadIdx.x;
  const int lane = t & 63, wv = t >> 6;
  const int c0 = blockIdx.x * 64;
  const int jq = blockIdx.y;
  const int m = lane & 15, q = lane >> 4;
  const int jp = t >> 4, cq = t & 15;    // j-pair 0..15 (j=2jp,2jp+1), c-quad
  f32x4 acc[8];
#pragma unroll
  for (int nt = 0; nt < 8; nt++) acc[nt] = (f32x4){0.f, 0.f, 0.f, 0.f};

  // preload it=0 (two adjacent j-rows, same c-quad)
  float4 pA = *(const float4*)&W2[(size_t)(jq * 512 + 2 * jp) * 4096 + c0 + cq * 4];
  float4 pB = *(const float4*)&W2[(size_t)(jq * 512 + 2 * jp + 1) * 4096 + c0 + cq * 4];

  for (int it = 0; it < 16; it++) {
    const int j0 = jq * 512 + it * 32;
    // pack + stage: row c = cq*4+i, dword slot jp holds (j=2jp, j=2jp+1)
    unsigned int d0 = cvtpk_bf16(pA.x, pB.x);
    unsigned int d1 = cvtpk_bf16(pA.y, pB.y);
    unsigned int d2 = cvtpk_bf16(pA.z, pB.z);
    unsigned int d3 = cvtpk_bf16(pA.w, pB.w);
    *(unsigned int*)&ldsT[(cq * 4 + 0) * 40 + jp * 2] = d0;
    *(unsigned int*)&ldsT[(cq * 4 + 1) * 40 + jp * 2] = d1;
    *(unsigned int*)&ldsT[(cq * 4 + 2) * 40 + jp * 2] = d2;
    *(unsigned int*)&ldsT[(cq * 4 + 3) * 40 + jp * 2] = d3;
    barrier_lgkm();
    bf16x8 av = *(const bf16x8*)&ldsT[(wv * 16 + m) * 40 + q * 8];
    // prefetch next iter while MFMA phase runs
    if (it + 1 < 16) {
      const int jn = j0 + 32;
      pA = *(const float4*)&W2[(size_t)(jn + 2 * jp) * 4096 + c0 + cq * 4];
      pB = *(const float4*)&W2[(size_t)(jn + 2 * jp + 1) * 4096 + c0 + cq * 4];
    }
#pragma unroll
    for (int nt = 0; nt < 8; nt++) {
      bf16x8 b = *(const bf16x8*)(W3b + (nt * 16 + m) * 4096 + j0 + q * 8);
      acc[nt] = __builtin_amdgcn_mfma_f32_16x16x32_bf16(av, b, acc[nt], 0, 0, 0);
    }
    barrier_lgkm();  // av reads drained; ldsT safe to overwrite next iter
  }
#pragma unroll
  for (int nt = 0; nt < 8; nt++)
#pragma unroll
    for (int r = 0; r < 4; r++)
      atomicAdd(&Mt[(size_t)(c0 + wv * 16 + q * 4 + r) * 128 + nt * 16 + m], acc[nt][r]);
}

// ---------------------------------------------------------------------------
// K3: out[b,k] = const[k] + sum_g Mt[g*256 + idx[b,g], k]  (unchanged)
// ---------------------------------------------------------------------------
__global__ __launch_bounds__(256) void k3_gather(const int* __restrict__ idxbuf,
                                                 const float* __restrict__ Mt,
                                                 const float* __restrict__ constv,
                                                 float* __restrict__ out) {
  const int t = threadIdx.x;
  const int w = t >> 6;
  const int lane = t & 63;
  const int b = blockIdx.x * 4 + w;
  float a0 = constv[lane];
  float a1 = constv[lane + 64];
  const int* ib = idxbuf + b * 16;
  int cg[16];
#pragma unroll
  for (int g = 0; g < 16; g++) cg[g] = g * 256 + ib[g];
#pragma unroll
  for (int g = 0; g < 16; g++) {
    const float* mrow = Mt + (size_t)cg[g] * 128;
    a0 += mrow[lane];
    a1 += mrow[lane + 64];
  }
  out[b * 128 + lane] = a0;
  out[b * 128 + lane + 64] = a1;
}

// ---------------------------------------------------------------------------
extern "C" void kernel_launch(void* const* d_in, const int* in_sizes, int n_in,
                              void* d_out, int out_size, void* d_ws, size_t ws_size,
                              hipStream_t stream) {
  const float* x  = (const float*)d_in[0];
  const float* W1 = (const float*)d_in[1];
  const float* b1 = (const float*)d_in[2];
  const float* W2 = (const float*)d_in[3];
  const float* b2 = (const float*)d_in[4];
  const float* W3 = (const float*)d_in[5];
  const float* b3 = (const float*)d_in[6];
  float* out = (float*)d_out;

  char* w = (char*)d_ws;
  int* idxbuf         = (int*)(w);                              // 2 MB
  unsigned short* W3b = (unsigned short*)(w + (2u << 20));      // 1 MB
  float* Mt           = (float*)(w + (3u << 20));               // 2 MB
  unsigned short* w1h = (unsigned short*)(w + (5u << 20));      // 1 MB (fp16 hi)
  unsigned short* w1l = (unsigned short*)(w + (6u << 20));      // 1 MB (fp16 lo)
  float* constv       = (float*)(w + (7u << 20));               // 512 B
  int* cntF           = (int*)(w + (7u << 20) + 1024);          // 4 B
  int* cnt2           = (int*)(w + (7u << 20) + 1280);          // 4 B (own line)
  int* listF          = (int*)(w + (7u << 20) + 4096);          // 128 KB
  int2* list2         = (int2*)(w + (7u << 20) + 139264);       // 256 KB

  kprep<<<1152, 256, 0, stream>>>(Mt, cntF, cnt2, W3, W3b, W1, w1h, w1l, b2, b3, constv);
  k1_mfma<<<512, 512, 0, stream>>>(x, w1h, w1l, b1, idxbuf, cntF, listF, cnt2, list2);
  k1_fix<<<2048, 256, 0, stream>>>(x, W1, b1, cntF, listF, cnt2, list2, idxbuf);
  k2_mfma<<<dim3(64, 8), 256, 0, stream>>>(W2, W3b, Mt);
  k3_gather<<<8192, 256, 0, stream>>>(idxbuf, Mt, constv, out);
}